// Round 6
// baseline (1366.272 us; speedup 1.0000x reference)
//
#include <hip/hip_runtime.h>
#include <math.h>

// Problem constants
constexpr int NB = 32, NL = 32, ND = 512, NHID = 512, NSTEPS = 31;
constexpr int NC5 = 2560;          // 5H
constexpr int BH = NB * NHID;      // 16384
constexpr int HSLOT_Z = 32;        // zero state slot (33 slots total)
constexpr int NGB = 160;           // GEMM worker blocks
constexpr int NMB = 32;            // merge worker blocks (1/batch)

constexpr float INV2048 = 1.f / 2048.f;

typedef _Float16 half8 __attribute__((ext_vector_type(8)));
typedef _Float16 half4 __attribute__((ext_vector_type(4)));
typedef float    f32x16 __attribute__((ext_vector_type(16)));

// ---------------- workspace layout (float offsets), ~30 MB ----------------
constexpr size_t OFF_GB0  = 0;                                   // [992][2560]
constexpr size_t OFF_GBS  = OFF_GB0 + (size_t)992 * NC5;         // [2][64][2560]
constexpr size_t OFF_PNH  = OFF_GBS + (size_t)2 * 64 * NC5;      // [31][32][512]
constexpr size_t OFF_PNC  = OFF_PNH + (size_t)31 * NB * NHID;
constexpr size_t OFF_CST  = OFF_PNC + (size_t)31 * NB * NHID;    // [33][32][512]
constexpr size_t OFF_HHI  = OFF_CST + (size_t)33 * NB * NHID;    // halves
constexpr size_t OFF_HLO  = OFF_HHI + (size_t)33 * NB * NHID / 2;
constexpr size_t OFF_WTH  = OFF_HLO + (size_t)33 * NB * NHID / 2;
constexpr size_t OFF_WTL  = OFF_WTH + (size_t)NC5 * 1024 / 2;
constexpr size_t OFF_SYNC = OFF_WTL + (size_t)NC5 * 1024 / 2;    // 64 ints used
constexpr size_t OFF_DESC = OFF_SYNC + 256;                      // int4[2][64]

__device__ __forceinline__ float sigf(float x) { return 1.f / (1.f + expf(-x)); }

__device__ __forceinline__ int aload(const int* p) {
    return __hip_atomic_load(p, __ATOMIC_ACQUIRE, __HIP_MEMORY_SCOPE_AGENT);
}
__device__ __forceinline__ void ainc(int* p) {
    __hip_atomic_fetch_add(p, 1, __ATOMIC_RELEASE, __HIP_MEMORY_SCOPE_AGENT);
}
__device__ __forceinline__ void wait_ge(const int* p, int target) {
    int guard = 0;
    while (aload(p) < target) {
        __builtin_amdgcn_s_sleep(2);
        if (++guard > 40000000) break;   // ~2s: degrade to wrong-answer, not hang
    }
}

// ---------------- init: zero slot + sync counters ----------------
__global__ __launch_bounds__(256) void init_kernel(
    _Float16* __restrict__ hHi, _Float16* __restrict__ hLo,
    float* __restrict__ cSt, int* __restrict__ sync_)
{
    const int tid = threadIdx.x;
    if (blockIdx.x == 0) {
        const size_t zb = (size_t)HSLOT_Z * NB * NHID;
        for (int i = tid; i < NB * NHID; i += 256) {
            hHi[zb + i] = (_Float16)0.f;
            hLo[zb + i] = (_Float16)0.f;
            cSt[zb + i] = 0.f;
        }
    } else {
        if (tid < 64) sync_[tid] = 0;
    }
}

// ---------------- W_comp -> transposed split fp16 planes ----------------
__global__ __launch_bounds__(256) void wsplit_kernel(
    const float* __restrict__ W, _Float16* __restrict__ Wth, _Float16* __restrict__ Wtl)
{
    __shared__ float t[32][33];
    const int n0 = blockIdx.x * 32, k0 = blockIdx.y * 32;
    const int tid = threadIdx.x;
    const int c = tid & 31, r8 = tid >> 5;
#pragma unroll
    for (int p = 0; p < 4; ++p) {
        int r = p * 8 + r8;
        t[r][c] = W[(size_t)(k0 + r) * NC5 + n0 + c];
    }
    __syncthreads();
    const int nl = tid >> 3, k4 = (tid & 7) * 4;
    half4 vh, vl;
#pragma unroll
    for (int i = 0; i < 4; ++i) {
        float v = t[k4 + i][nl];
        _Float16 hh = (_Float16)v;
        vh[i] = hh;
        vl[i] = (_Float16)((v - (float)hh) * 2048.f);
    }
    size_t o = (size_t)(n0 + nl) * 1024 + k0 + k4;
    *(half4*)&Wth[o] = vh;
    *(half4*)&Wtl[o] = vl;
}

// ---------------- word GEMM: leaves -> state slots 0..31 ----------------
__global__ __launch_bounds__(256) void word_gemm64(
    const float* __restrict__ A, const float* __restrict__ W,
    const float* __restrict__ bias,
    _Float16* __restrict__ hi0, _Float16* __restrict__ lo0,
    float* __restrict__ cst, float* __restrict__ out)
{
    const int m0 = blockIdx.x * 64;
    const int n0 = blockIdx.y * 64;
    const int tid = threadIdx.x;
    const int tx = tid & 15, ty = tid >> 4;
    __shared__ float As[16][64];
    __shared__ float Bs[16][64];
    float acc[4][4];
#pragma unroll
    for (int i = 0; i < 4; ++i)
#pragma unroll
        for (int j = 0; j < 4; ++j) acc[i][j] = 0.f;

    for (int kt = 0; kt < ND; kt += 16) {
        {
            int row = tid >> 2, kq = tid & 3;
            float4 v = *(const float4*)(A + (size_t)(m0 + row) * ND + kt + kq * 4);
            As[kq * 4 + 0][row] = v.x;
            As[kq * 4 + 1][row] = v.y;
            As[kq * 4 + 2][row] = v.z;
            As[kq * 4 + 3][row] = v.w;
            int kr = tid >> 4, nq = tid & 15;
            float4 vb = *(const float4*)(W + (size_t)(kt + kr) * 1024 + n0 + nq * 4);
            *(float4*)&Bs[kr][nq * 4] = vb;
        }
        __syncthreads();
#pragma unroll
        for (int kk = 0; kk < 16; ++kk) {
            float a0 = As[kk][ty * 4 + 0], a1 = As[kk][ty * 4 + 1];
            float a2 = As[kk][ty * 4 + 2], a3 = As[kk][ty * 4 + 3];
            float4 bv = *(float4*)&Bs[kk][tx * 4];
            acc[0][0] = fmaf(a0, bv.x, acc[0][0]); acc[0][1] = fmaf(a0, bv.y, acc[0][1]);
            acc[0][2] = fmaf(a0, bv.z, acc[0][2]); acc[0][3] = fmaf(a0, bv.w, acc[0][3]);
            acc[1][0] = fmaf(a1, bv.x, acc[1][0]); acc[1][1] = fmaf(a1, bv.y, acc[1][1]);
            acc[1][2] = fmaf(a1, bv.z, acc[1][2]); acc[1][3] = fmaf(a1, bv.w, acc[1][3]);
            acc[2][0] = fmaf(a2, bv.x, acc[2][0]); acc[2][1] = fmaf(a2, bv.y, acc[2][1]);
            acc[2][2] = fmaf(a2, bv.z, acc[2][2]); acc[2][3] = fmaf(a2, bv.w, acc[2][3]);
            acc[3][0] = fmaf(a3, bv.x, acc[3][0]); acc[3][1] = fmaf(a3, bv.y, acc[3][1]);
            acc[3][2] = fmaf(a3, bv.z, acc[3][2]); acc[3][3] = fmaf(a3, bv.w, acc[3][3]);
        }
        __syncthreads();
    }
    float* nodes = out + 2 * BH;
#pragma unroll
    for (int i = 0; i < 4; ++i) {
        int r = m0 + ty * 4 + i;
        int b = r >> 5, l = r & 31;
#pragma unroll
        for (int jn = 0; jn < 4; ++jn) {
            int n = n0 + tx * 4 + jn;
            float v = acc[i][jn] + bias[n];
            if (n < NHID) {
                size_t si = ((size_t)l * NB + b) * NHID + n;
                _Float16 hh = (_Float16)v;
                hi0[si] = hh;
                lo0[si] = (_Float16)((v - (float)hh) * 2048.f);
                nodes[((size_t)b * 63 + l) * NHID + n] = v;
            } else {
                cst[((size_t)l * NB + b) * NHID + (n - NHID)] = v;
            }
        }
    }
}

// 32x32 split-fp16 3-product MFMA tile; K split over 4 waves; cross-wave
// reduce through LDS; raw gates (no bias) to dstRow0.
__device__ __forceinline__ void gemm_tile32(
    const _Float16* __restrict__ aHiP, const _Float16* __restrict__ aLoP,
    const _Float16* __restrict__ bHiP, const _Float16* __restrict__ bLoP,
    float* __restrict__ red, float* __restrict__ dstRow0, int ntOff,
    int kw, int l5, int ln, int tid)
{
    f32x16 acc1 = (f32x16)0.f, acc2 = (f32x16)0.f;
#pragma unroll
    for (int ks = 0; ks < 16; ++ks) {
        const int ko = ks * 16;
        half8 Ah = *(const half8*)(aHiP + ko);
        half8 Al = *(const half8*)(aLoP + ko);
        half8 Bh = *(const half8*)(bHiP + ko);
        half8 Bl = *(const half8*)(bLoP + ko);
        acc1 = __builtin_amdgcn_mfma_f32_32x32x16_f16(Ah, Bh, acc1, 0, 0, 0);
        acc2 = __builtin_amdgcn_mfma_f32_32x32x16_f16(Ah, Bl, acc2, 0, 0, 0);
        acc2 = __builtin_amdgcn_mfma_f32_32x32x16_f16(Al, Bh, acc2, 0, 0, 0);
    }
    __syncthreads();                      // red free from previous use
#pragma unroll
    for (int a = 0; a < 16; ++a) {
        int row = (a & 3) + 8 * (a >> 2) + 4 * l5;
        red[(kw * 32 + row) * 32 + ln] = acc1[a] + acc2[a] * INV2048;
    }
    __syncthreads();
    {
        const int row = tid >> 3, c0 = (tid & 7) * 4;
        float4 s;
        s.x = (red[(0 * 32 + row) * 32 + c0 + 0] + red[(1 * 32 + row) * 32 + c0 + 0])
            + (red[(2 * 32 + row) * 32 + c0 + 0] + red[(3 * 32 + row) * 32 + c0 + 0]);
        s.y = (red[(0 * 32 + row) * 32 + c0 + 1] + red[(1 * 32 + row) * 32 + c0 + 1])
            + (red[(2 * 32 + row) * 32 + c0 + 1] + red[(3 * 32 + row) * 32 + c0 + 1]);
        s.z = (red[(0 * 32 + row) * 32 + c0 + 2] + red[(1 * 32 + row) * 32 + c0 + 2])
            + (red[(2 * 32 + row) * 32 + c0 + 2] + red[(3 * 32 + row) * 32 + c0 + 2]);
        s.w = (red[(0 * 32 + row) * 32 + c0 + 3] + red[(1 * 32 + row) * 32 + c0 + 3])
            + (red[(2 * 32 + row) * 32 + c0 + 3] + red[(3 * 32 + row) * 32 + c0 + 3]);
        *(float4*)&dstRow0[(size_t)row * NC5 + ntOff + c0] = s;
    }
}

// ---------------- the persistent tree kernel ----------------
// Blocks 0..159: GEMM workers (nt = blk%80 fixed -> L2-local W slice).
// Blocks 160..191: merge workers (1/batch): act fresh pairs, argmax, merge,
// bookkeeping in LDS, publish next-step descriptors.
// Sync: per-step monotone counters, agent-scope acquire/release atomics.
__global__ __launch_bounds__(256) void tree_persist(
    _Float16* __restrict__ hHi, _Float16* __restrict__ hLo, float* __restrict__ cSt,
    const _Float16* __restrict__ Wth, const _Float16* __restrict__ Wtl,
    const float* __restrict__ bias, const float* __restrict__ q,
    const int* __restrict__ len,
    float* __restrict__ gb0, float* __restrict__ gbS,
    float* __restrict__ pnh, float* __restrict__ pnc,
    int4* __restrict__ dsc, int* __restrict__ sync_, float* __restrict__ out)
{
    int* pubCnt = sync_;        // [32]: pubCnt[i] -> 32 when step-i descs ready
    int* gdone  = sync_ + 32;   // [32]: gdone[i]  -> 160 when step-i gates ready
    const int blk = blockIdx.x, tid = threadIdx.x;

    if (blk < NGB) {
        // ================= GEMM worker =================
        __shared__ float red[4 * 32 * 32];
        const int kw = tid >> 6, lane = tid & 63;
        const int l5 = lane >> 5, ln = lane & 31;
        const int koff = (kw & 1) * 256 + l5 * 8;   // k offset inside one 512 half
        const int nt = blk % 80;
        // wave kw covers global k chunk kw*256 = (kw>>1)*512 + (kw&1)*256
        const _Float16* bH = Wth + ((size_t)(nt * 32 + ln)) * 1024 + (kw >> 1) * 512 + koff;
        const _Float16* bL = Wtl + ((size_t)(nt * 32 + ln)) * 1024 + (kw >> 1) * 512 + koff;
        // A uses (kw<2)? left : right state vector with koff inside 512.

        // ---- step 0: all 992 pairs (j = mt, b = ln, left = mt, right = mt+1)
        for (int job = blk; job < 2480; job += NGB) {
            const int mt = job / 80;
            const int hs = (kw < 2) ? mt : mt + 1;
            const _Float16* aH = hHi + ((size_t)hs * NB + ln) * NHID + koff;
            const _Float16* aL = hLo + ((size_t)hs * NB + ln) * NHID + koff;
            gemm_tile32(aH, aL, bH, bL, red, gb0 + (size_t)(mt * 32) * NC5,
                        nt * 32, kw, l5, ln, tid);
        }
        __syncthreads();
        if (tid == 0) ainc(&gdone[0]);

        // ---- steps 1..30: 64 fresh rows (2/batch), desc-driven
        const int mt = blk / 80;             // 0..1
        const int r  = mt * 32 + ln;
        const int bb = r >> 1;
        for (int i = 1; i <= 30; ++i) {
            if (tid == 0) wait_ge(&pubCnt[i], 32);
            __syncthreads();
            const int p = i & 1;
            const int4 d = dsc[p * 64 + r];  // {slot, left, right, active}
            const int hs = (kw < 2) ? d.y : d.z;
            const _Float16* aH = hHi + ((size_t)hs * NB + bb) * NHID + koff;
            const _Float16* aL = hLo + ((size_t)hs * NB + bb) * NHID + koff;
            gemm_tile32(aH, aL, bH, bL, red, gbS + (size_t)(p * 64 + mt * 32) * NC5,
                        nt * 32, kw, l5, ln, tid);
            __syncthreads();
            if (tid == 0) ainc(&gdone[i]);
        }
    } else if (blk < NGB + NMB) {
        // ================= merge worker (batch b) =================
        const int b = blk - NGB;
        __shared__ int pidx_s[32], hidx_s[32];
        __shared__ float plog_s[31];
        __shared__ float lred[4];
        __shared__ int s_k, s_nf, s_fslot[2], s_fls[2], s_frs[2];
        if (tid < 32) { pidx_s[tid] = min(tid, 30); hidx_s[tid] = tid; }
        __syncthreads();
        const int lenb = len[b];

        for (int i = 0; i <= 30; ++i) {
            if (tid == 0) wait_ge(&gdone[i], NGB);
            __syncthreads();
            const int p = i & 1;

            // Phase A: act + logit for fresh pairs
            const int nf = (i == 0) ? 31 : s_nf;
            for (int f = 0; f < nf; ++f) {
                int slot, ls, rs; const float* gr;
                if (i == 0) { slot = f; ls = f; rs = f + 1;
                              gr = gb0 + ((size_t)(f * 32 + b)) * NC5; }
                else        { slot = s_fslot[f]; ls = s_fls[f]; rs = s_frs[f];
                              gr = gbS + ((size_t)(p * 64 + 2 * b + f)) * NC5; }
                const float* clp = cSt + ((size_t)ls * NB + b) * NHID;
                const float* crp = cSt + ((size_t)rs * NB + b) * NHID;
                float lpart = 0.f;
                for (int h = tid; h < NHID; h += 256) {
                    float ig = gr[h]          + bias[h];
                    float fl = gr[512 + h]    + bias[512 + h];
                    float fr = gr[1024 + h]   + bias[1024 + h];
                    float u  = gr[1536 + h]   + bias[1536 + h];
                    float o  = gr[2048 + h]   + bias[2048 + h];
                    float cl = clp[h], cr = crp[h];
                    float c  = cl * sigf(fl + 1.f) + cr * sigf(fr + 1.f)
                             + tanhf(u) * sigf(ig);
                    float hh = sigf(o) * tanhf(c);
                    size_t po = ((size_t)slot * NB + b) * NHID + h;
                    pnh[po] = hh;
                    pnc[po] = c;
                    lpart = fmaf(hh, q[h], lpart);
                }
#pragma unroll
                for (int off = 32; off > 0; off >>= 1) lpart += __shfl_down(lpart, off);
                if ((tid & 63) == 0) lred[tid >> 6] = lpart;
                __syncthreads();
                if (tid == 0) plog_s[slot] = (lred[0] + lred[1]) + (lred[2] + lred[3]);
                __syncthreads();
            }

            // Phase B: argmax (first-index tie-break)
            const int actb = lenb - 1 - i;
            const int merge = actb >= 1;
            if (tid < 64) {
                float v = -1e30f;
                int idx = tid;
                if (tid < actb && tid < 31) v = plog_s[pidx_s[tid]];
#pragma unroll
                for (int off = 32; off > 0; off >>= 1) {
                    float ov = __shfl_down(v, off);
                    int   oi = __shfl_down(idx, off);
                    if (ov > v || (ov == v && oi < idx)) { v = ov; idx = oi; }
                }
                if (tid == 0) s_k = idx;
            }
            __syncthreads();
            const int k = s_k;
            const int last = (i == 30);

            // Phase C: node output + new state (or final hf/cf)
            float* noderow = out + 2 * BH + ((size_t)b * 63 + 32 + i) * NHID;
            if (merge) {
                const int kslot = pidx_s[k];
                const int ns = hidx_s[k];
                for (int h = tid; h < NHID; h += 256) {
                    size_t po = ((size_t)kslot * NB + b) * NHID + h;
                    float x = pnh[po], cc = pnc[po];
                    _Float16 hh = (_Float16)x;
                    size_t so = ((size_t)ns * NB + b) * NHID + h;
                    hHi[so] = hh;
                    hLo[so] = (_Float16)((x - (float)hh) * 2048.f);
                    cSt[so] = cc;
                    noderow[h] = x;
                    if (last) { out[b * NHID + h] = x; out[BH + b * NHID + h] = cc; }
                }
            } else {
                const int s0p = pidx_s[0], s0h = hidx_s[0];
                for (int h = tid; h < NHID; h += 256) {
                    if (!last) {
                        noderow[h] = pnh[((size_t)s0p * NB + b) * NHID + h];
                    } else {
                        size_t so = ((size_t)s0h * NB + b) * NHID + h;
                        float x = (float)hHi[so] + (float)hLo[so] * INV2048;
                        noderow[h] = x;
                        out[b * NHID + h] = x;
                        out[BH + b * NHID + h] = cSt[so];
                    }
                }
            }
            __syncthreads();   // drain state stores before publish

            // Phase D: bookkeeping + publish next step
            if (i < 30) {
                if (tid == 0) {
                    const int np = (i + 1) & 1;
                    if (merge) {
                        const int sp_k = pidx_s[k], sh_k = hidx_s[k];
                        const int sh_k2 = (k + 2 <= 31) ? hidx_s[k + 2] : HSLOT_Z;
                        const int nd = (k >= 1) ? 2 : 1;
                        int sp_km1 = 0, sh_km1 = 0;
                        if (k >= 1) { sp_km1 = pidx_s[k - 1]; sh_km1 = hidx_s[k - 1]; }
                        const int sp_k1 = pidx_s[k + 1];   // k<=30 -> in-bounds
                        for (int j2 = k + 1; j2 <= 29; ++j2) pidx_s[j2] = pidx_s[j2 + 1];
                        if (k < 30) pidx_s[30] = sp_k1;
                        for (int pp = k + 1; pp <= 30; ++pp) hidx_s[pp] = hidx_s[pp + 1];
                        hidx_s[31] = HSLOT_Z;
                        if (nd == 2) {
                            dsc[np * 64 + 2 * b]     = make_int4(sp_km1, sh_km1, sh_k, 1);
                            dsc[np * 64 + 2 * b + 1] = make_int4(sp_k, sh_k, sh_k2, 1);
                            s_fslot[0] = sp_km1; s_fls[0] = sh_km1; s_frs[0] = sh_k;
                            s_fslot[1] = sp_k;   s_fls[1] = sh_k;   s_frs[1] = sh_k2;
                        } else {
                            dsc[np * 64 + 2 * b]     = make_int4(sp_k, sh_k, sh_k2, 1);
                            dsc[np * 64 + 2 * b + 1] = make_int4(0, HSLOT_Z, HSLOT_Z, 0);
                            s_fslot[0] = sp_k; s_fls[0] = sh_k; s_frs[0] = sh_k2;
                        }
                        s_nf = nd;
                    } else {
                        dsc[np * 64 + 2 * b]     = make_int4(0, HSLOT_Z, HSLOT_Z, 0);
                        dsc[np * 64 + 2 * b + 1] = make_int4(0, HSLOT_Z, HSLOT_Z, 0);
                        s_nf = 0;
                    }
                    ainc(&pubCnt[i + 1]);
                }
                __syncthreads();
            }
        }
    }
}

extern "C" void kernel_launch(void* const* d_in, const int* in_sizes, int n_in,
                              void* d_out, int out_size, void* d_ws, size_t ws_size,
                              hipStream_t stream) {
    const float* inp    = (const float*)d_in[0];
    const int*   length = (const int*)d_in[1];
    const float* W_word = (const float*)d_in[2];
    const float* b_word = (const float*)d_in[3];
    const float* W_comp = (const float*)d_in[4];
    const float* b_comp = (const float*)d_in[5];
    const float* q      = (const float*)d_in[6];
    float* out = (float*)d_out;
    float* ws  = (float*)d_ws;

    float*     gb0  = ws + OFF_GB0;
    float*     gbS  = ws + OFF_GBS;
    float*     pnh  = ws + OFF_PNH;
    float*     pnc  = ws + OFF_PNC;
    float*     cSt  = ws + OFF_CST;
    _Float16*  hHi  = (_Float16*)(ws + OFF_HHI);
    _Float16*  hLo  = (_Float16*)(ws + OFF_HLO);
    _Float16*  Wth  = (_Float16*)(ws + OFF_WTH);
    _Float16*  Wtl  = (_Float16*)(ws + OFF_WTL);
    int*       sy   = (int*)(ws + OFF_SYNC);
    int4*      dsc  = (int4*)(ws + OFF_DESC);

    init_kernel<<<2, 256, 0, stream>>>(hHi, hLo, cSt, sy);
    wsplit_kernel<<<dim3(NC5 / 32, 1024 / 32), 256, 0, stream>>>(W_comp, Wth, Wtl);
    word_gemm64<<<dim3(16, 16), 256, 0, stream>>>(inp, W_word, b_word,
                                                  hHi, hLo, cSt, out);
    tree_persist<<<NGB + NMB, 256, 0, stream>>>(hHi, hLo, cSt, Wth, Wtl,
                                                b_comp, q, length,
                                                gb0, gbS, pnh, pnc,
                                                dsc, sy, out);
}

// Round 7
// 1144.923 us; speedup vs baseline: 1.1933x; 1.1933x over previous
//
#include <hip/hip_runtime.h>
#include <math.h>

// Problem constants
constexpr int NB = 32, NL = 32, ND = 512, NHID = 512, NSTEPS = 31;
constexpr int NC5 = 2560;          // 5H
constexpr int BH = NB * NHID;      // 16384
constexpr int HSLOT_Z = 32;        // zero state slot (33 slots total)
constexpr int NGB = 80;            // GEMM worker blocks (1 per n-tile)
constexpr int NMB = 32;            // merge worker blocks (1/batch)

constexpr float INV2048 = 1.f / 2048.f;

typedef _Float16 half8 __attribute__((ext_vector_type(8)));
typedef _Float16 half4 __attribute__((ext_vector_type(4)));
typedef float    f32x16 __attribute__((ext_vector_type(16)));

// ---------------- workspace layout (float offsets), ~30 MB ----------------
constexpr size_t OFF_GB0  = 0;                                   // [992][2560]
constexpr size_t OFF_GBS  = OFF_GB0 + (size_t)992 * NC5;         // [2][64][2560]
constexpr size_t OFF_PNH  = OFF_GBS + (size_t)2 * 64 * NC5;      // [31][32][512]
constexpr size_t OFF_PNC  = OFF_PNH + (size_t)31 * NB * NHID;
constexpr size_t OFF_CST  = OFF_PNC + (size_t)31 * NB * NHID;    // [33][32][512]
constexpr size_t OFF_HHI  = OFF_CST + (size_t)33 * NB * NHID;    // halves
constexpr size_t OFF_HLO  = OFF_HHI + (size_t)33 * NB * NHID / 2;
constexpr size_t OFF_WTH  = OFF_HLO + (size_t)33 * NB * NHID / 2;
constexpr size_t OFF_WTL  = OFF_WTH + (size_t)NC5 * 1024 / 2;
constexpr size_t OFF_SYNC = OFF_WTL + (size_t)NC5 * 1024 / 2;    // 64 ints used
constexpr size_t OFF_DESC = OFF_SYNC + 256;                      // int4[2][64]

__device__ __forceinline__ float sigf(float x) { return 1.f / (1.f + expf(-x)); }

// Poll with a RELAXED agent-scope RMW: serviced at the coherence point (fresh
// value) with NO per-iteration cache invalidation. Pair with a single explicit
// acquire fence after the wait succeeds (R6's per-iteration acquire-invalidate
// storm was the 42 us/step).
__device__ __forceinline__ int apoll(int* p) {
    return __hip_atomic_fetch_add(p, 0, __ATOMIC_RELAXED, __HIP_MEMORY_SCOPE_AGENT);
}
__device__ __forceinline__ void ainc_relaxed(int* p) {
    __hip_atomic_fetch_add(p, 1, __ATOMIC_RELAXED, __HIP_MEMORY_SCOPE_AGENT);
}
__device__ __forceinline__ void wait_ge(int* p, int target) {
    int guard = 0;
    while (apoll(p) < target) {
        __builtin_amdgcn_s_sleep(8);
        if (++guard > 10000000) break;   // ~2s: degrade to wrong-answer, not hang
    }
}

// ---------------- init: zero slot + sync counters ----------------
__global__ __launch_bounds__(256) void init_kernel(
    _Float16* __restrict__ hHi, _Float16* __restrict__ hLo,
    float* __restrict__ cSt, int* __restrict__ sync_)
{
    const int tid = threadIdx.x;
    if (blockIdx.x == 0) {
        const size_t zb = (size_t)HSLOT_Z * NB * NHID;
        for (int i = tid; i < NB * NHID; i += 256) {
            hHi[zb + i] = (_Float16)0.f;
            hLo[zb + i] = (_Float16)0.f;
            cSt[zb + i] = 0.f;
        }
    } else {
        if (tid < 64) sync_[tid] = 0;
    }
}

// ---------------- W_comp -> transposed split fp16 planes ----------------
__global__ __launch_bounds__(256) void wsplit_kernel(
    const float* __restrict__ W, _Float16* __restrict__ Wth, _Float16* __restrict__ Wtl)
{
    __shared__ float t[32][33];
    const int n0 = blockIdx.x * 32, k0 = blockIdx.y * 32;
    const int tid = threadIdx.x;
    const int c = tid & 31, r8 = tid >> 5;
#pragma unroll
    for (int p = 0; p < 4; ++p) {
        int r = p * 8 + r8;
        t[r][c] = W[(size_t)(k0 + r) * NC5 + n0 + c];
    }
    __syncthreads();
    const int nl = tid >> 3, k4 = (tid & 7) * 4;
    half4 vh, vl;
#pragma unroll
    for (int i = 0; i < 4; ++i) {
        float v = t[k4 + i][nl];
        _Float16 hh = (_Float16)v;
        vh[i] = hh;
        vl[i] = (_Float16)((v - (float)hh) * 2048.f);
    }
    size_t o = (size_t)(n0 + nl) * 1024 + k0 + k4;
    *(half4*)&Wth[o] = vh;
    *(half4*)&Wtl[o] = vl;
}

// ---------------- word GEMM: leaves -> state slots 0..31 ----------------
__global__ __launch_bounds__(256) void word_gemm64(
    const float* __restrict__ A, const float* __restrict__ W,
    const float* __restrict__ bias,
    _Float16* __restrict__ hi0, _Float16* __restrict__ lo0,
    float* __restrict__ cst, float* __restrict__ out)
{
    const int m0 = blockIdx.x * 64;
    const int n0 = blockIdx.y * 64;
    const int tid = threadIdx.x;
    const int tx = tid & 15, ty = tid >> 4;
    __shared__ float As[16][64];
    __shared__ float Bs[16][64];
    float acc[4][4];
#pragma unroll
    for (int i = 0; i < 4; ++i)
#pragma unroll
        for (int j = 0; j < 4; ++j) acc[i][j] = 0.f;

    for (int kt = 0; kt < ND; kt += 16) {
        {
            int row = tid >> 2, kq = tid & 3;
            float4 v = *(const float4*)(A + (size_t)(m0 + row) * ND + kt + kq * 4);
            As[kq * 4 + 0][row] = v.x;
            As[kq * 4 + 1][row] = v.y;
            As[kq * 4 + 2][row] = v.z;
            As[kq * 4 + 3][row] = v.w;
            int kr = tid >> 4, nq = tid & 15;
            float4 vb = *(const float4*)(W + (size_t)(kt + kr) * 1024 + n0 + nq * 4);
            *(float4*)&Bs[kr][nq * 4] = vb;
        }
        __syncthreads();
#pragma unroll
        for (int kk = 0; kk < 16; ++kk) {
            float a0 = As[kk][ty * 4 + 0], a1 = As[kk][ty * 4 + 1];
            float a2 = As[kk][ty * 4 + 2], a3 = As[kk][ty * 4 + 3];
            float4 bv = *(float4*)&Bs[kk][tx * 4];
            acc[0][0] = fmaf(a0, bv.x, acc[0][0]); acc[0][1] = fmaf(a0, bv.y, acc[0][1]);
            acc[0][2] = fmaf(a0, bv.z, acc[0][2]); acc[0][3] = fmaf(a0, bv.w, acc[0][3]);
            acc[1][0] = fmaf(a1, bv.x, acc[1][0]); acc[1][1] = fmaf(a1, bv.y, acc[1][1]);
            acc[1][2] = fmaf(a1, bv.z, acc[1][2]); acc[1][3] = fmaf(a1, bv.w, acc[1][3]);
            acc[2][0] = fmaf(a2, bv.x, acc[2][0]); acc[2][1] = fmaf(a2, bv.y, acc[2][1]);
            acc[2][2] = fmaf(a2, bv.z, acc[2][2]); acc[2][3] = fmaf(a2, bv.w, acc[2][3]);
            acc[3][0] = fmaf(a3, bv.x, acc[3][0]); acc[3][1] = fmaf(a3, bv.y, acc[3][1]);
            acc[3][2] = fmaf(a3, bv.z, acc[3][2]); acc[3][3] = fmaf(a3, bv.w, acc[3][3]);
        }
        __syncthreads();
    }
    float* nodes = out + 2 * BH;
#pragma unroll
    for (int i = 0; i < 4; ++i) {
        int r = m0 + ty * 4 + i;
        int b = r >> 5, l = r & 31;
#pragma unroll
        for (int jn = 0; jn < 4; ++jn) {
            int n = n0 + tx * 4 + jn;
            float v = acc[i][jn] + bias[n];
            if (n < NHID) {
                size_t si = ((size_t)l * NB + b) * NHID + n;
                _Float16 hh = (_Float16)v;
                hi0[si] = hh;
                lo0[si] = (_Float16)((v - (float)hh) * 2048.f);
                nodes[((size_t)b * 63 + l) * NHID + n] = v;
            } else {
                cst[((size_t)l * NB + b) * NHID + (n - NHID)] = v;
            }
        }
    }
}

// 32x32 split-fp16 3-product MFMA tile; K split over 4 waves; cross-wave
// reduce through LDS; raw gates (no bias) to dstRow0.
__device__ __forceinline__ void gemm_tile32(
    const _Float16* __restrict__ aHiP, const _Float16* __restrict__ aLoP,
    const _Float16* __restrict__ bHiP, const _Float16* __restrict__ bLoP,
    float* __restrict__ red, float* __restrict__ dstRow0, int ntOff,
    int kw, int l5, int ln, int tid)
{
    f32x16 acc1 = (f32x16)0.f, acc2 = (f32x16)0.f;
#pragma unroll
    for (int ks = 0; ks < 16; ++ks) {
        const int ko = ks * 16;
        half8 Ah = *(const half8*)(aHiP + ko);
        half8 Al = *(const half8*)(aLoP + ko);
        half8 Bh = *(const half8*)(bHiP + ko);
        half8 Bl = *(const half8*)(bLoP + ko);
        acc1 = __builtin_amdgcn_mfma_f32_32x32x16_f16(Ah, Bh, acc1, 0, 0, 0);
        acc2 = __builtin_amdgcn_mfma_f32_32x32x16_f16(Ah, Bl, acc2, 0, 0, 0);
        acc2 = __builtin_amdgcn_mfma_f32_32x32x16_f16(Al, Bh, acc2, 0, 0, 0);
    }
    __syncthreads();                      // red free from previous use
#pragma unroll
    for (int a = 0; a < 16; ++a) {
        int row = (a & 3) + 8 * (a >> 2) + 4 * l5;
        red[(kw * 32 + row) * 32 + ln] = acc1[a] + acc2[a] * INV2048;
    }
    __syncthreads();
    {
        const int row = tid >> 3, c0 = (tid & 7) * 4;
        float4 s;
        s.x = (red[(0 * 32 + row) * 32 + c0 + 0] + red[(1 * 32 + row) * 32 + c0 + 0])
            + (red[(2 * 32 + row) * 32 + c0 + 0] + red[(3 * 32 + row) * 32 + c0 + 0]);
        s.y = (red[(0 * 32 + row) * 32 + c0 + 1] + red[(1 * 32 + row) * 32 + c0 + 1])
            + (red[(2 * 32 + row) * 32 + c0 + 1] + red[(3 * 32 + row) * 32 + c0 + 1]);
        s.z = (red[(0 * 32 + row) * 32 + c0 + 2] + red[(1 * 32 + row) * 32 + c0 + 2])
            + (red[(2 * 32 + row) * 32 + c0 + 2] + red[(3 * 32 + row) * 32 + c0 + 2]);
        s.w = (red[(0 * 32 + row) * 32 + c0 + 3] + red[(1 * 32 + row) * 32 + c0 + 3])
            + (red[(2 * 32 + row) * 32 + c0 + 3] + red[(3 * 32 + row) * 32 + c0 + 3]);
        *(float4*)&dstRow0[(size_t)row * NC5 + ntOff + c0] = s;
    }
}

// ---------------- the persistent tree kernel ----------------
// Blocks 0..79: GEMM workers (nt = blk fixed -> L2-local W slice; both m-tiles).
// Blocks 80..111: merge workers (1/batch).
// Sync: per-step monotone counters; RELAXED RMW polling; ONE acquire fence
// after each successful wait; ONE release fence before each increment.
__global__ __launch_bounds__(256) void tree_persist(
    _Float16* __restrict__ hHi, _Float16* __restrict__ hLo, float* __restrict__ cSt,
    const _Float16* __restrict__ Wth, const _Float16* __restrict__ Wtl,
    const float* __restrict__ bias, const float* __restrict__ q,
    const int* __restrict__ len,
    float* __restrict__ gb0, float* __restrict__ gbS,
    float* __restrict__ pnh, float* __restrict__ pnc,
    int4* __restrict__ dsc, int* __restrict__ sync_, float* __restrict__ out)
{
    int* pubCnt = sync_;        // [32]: pubCnt[i] -> 32 when step-i descs ready
    int* gdone  = sync_ + 32;   // [32]: gdone[i]  -> 80 when step-i gates ready
    const int blk = blockIdx.x, tid = threadIdx.x;

    if (blk < NGB) {
        // ================= GEMM worker =================
        __shared__ float red[4 * 32 * 32];
        const int kw = tid >> 6, lane = tid & 63;
        const int l5 = lane >> 5, ln = lane & 31;
        const int koff = (kw & 1) * 256 + l5 * 8;   // k offset inside one 512 half
        const int nt = blk;
        // wave kw covers global k chunk kw*256 = (kw>>1)*512 + (kw&1)*256
        const _Float16* bH = Wth + ((size_t)(nt * 32 + ln)) * 1024 + (kw >> 1) * 512 + koff;
        const _Float16* bL = Wtl + ((size_t)(nt * 32 + ln)) * 1024 + (kw >> 1) * 512 + koff;

        // ---- step 0: all 992 pairs (j = mt, b = ln, left = mt, right = mt+1)
        for (int job = blk; job < 2480; job += NGB) {
            const int mt = job / 80;           // 0..30 (nt = job % 80 == blk)
            const int hs = (kw < 2) ? mt : mt + 1;
            const _Float16* aH = hHi + ((size_t)hs * NB + ln) * NHID + koff;
            const _Float16* aL = hLo + ((size_t)hs * NB + ln) * NHID + koff;
            gemm_tile32(aH, aL, bH, bL, red, gb0 + (size_t)(mt * 32) * NC5,
                        nt * 32, kw, l5, ln, tid);
        }
        __syncthreads();
        __builtin_amdgcn_fence(__ATOMIC_RELEASE, "agent");   // flush gb0
        if (tid == 0) ainc_relaxed(&gdone[0]);

        // ---- steps 1..30: 64 fresh rows (2/batch), desc-driven, both m-tiles
        for (int i = 1; i <= 30; ++i) {
            if (tid == 0) wait_ge(&pubCnt[i], 32);
            __syncthreads();
            __builtin_amdgcn_fence(__ATOMIC_ACQUIRE, "agent");  // fresh dsc/state
            const int p = i & 1;
#pragma unroll
            for (int mt = 0; mt < 2; ++mt) {
                const int r = mt * 32 + ln;
                const int bb = r >> 1;
                const int4 d = dsc[p * 64 + r];  // {slot, left, right, active}
                const int hs = (kw < 2) ? d.y : d.z;
                const _Float16* aH = hHi + ((size_t)hs * NB + bb) * NHID + koff;
                const _Float16* aL = hLo + ((size_t)hs * NB + bb) * NHID + koff;
                gemm_tile32(aH, aL, bH, bL, red, gbS + (size_t)(p * 64 + mt * 32) * NC5,
                            nt * 32, kw, l5, ln, tid);
            }
            __syncthreads();
            __builtin_amdgcn_fence(__ATOMIC_RELEASE, "agent");  // flush gbS
            if (tid == 0) ainc_relaxed(&gdone[i]);
        }
    } else if (blk < NGB + NMB) {
        // ================= merge worker (batch b) =================
        const int b = blk - NGB;
        __shared__ int pidx_s[32], hidx_s[32];
        __shared__ float plog_s[31];
        __shared__ float lred[4];
        __shared__ int s_k, s_nf, s_fslot[2], s_fls[2], s_frs[2];
        if (tid < 32) { pidx_s[tid] = min(tid, 30); hidx_s[tid] = tid; }
        __syncthreads();
        const int lenb = len[b];

        for (int i = 0; i <= 30; ++i) {
            if (tid == 0) wait_ge(&gdone[i], NGB);
            __syncthreads();
            __builtin_amdgcn_fence(__ATOMIC_ACQUIRE, "agent");  // fresh gates
            const int p = i & 1;

            // Phase A: act + logit for fresh pairs
            const int nf = (i == 0) ? 31 : s_nf;
            for (int f = 0; f < nf; ++f) {
                int slot, ls, rs; const float* gr;
                if (i == 0) { slot = f; ls = f; rs = f + 1;
                              gr = gb0 + ((size_t)(f * 32 + b)) * NC5; }
                else        { slot = s_fslot[f]; ls = s_fls[f]; rs = s_frs[f];
                              gr = gbS + ((size_t)(p * 64 + 2 * b + f)) * NC5; }
                const float* clp = cSt + ((size_t)ls * NB + b) * NHID;
                const float* crp = cSt + ((size_t)rs * NB + b) * NHID;
                float lpart = 0.f;
                for (int h = tid; h < NHID; h += 256) {
                    float ig = gr[h]          + bias[h];
                    float fl = gr[512 + h]    + bias[512 + h];
                    float fr = gr[1024 + h]   + bias[1024 + h];
                    float u  = gr[1536 + h]   + bias[1536 + h];
                    float o  = gr[2048 + h]   + bias[2048 + h];
                    float cl = clp[h], cr = crp[h];
                    float c  = cl * sigf(fl + 1.f) + cr * sigf(fr + 1.f)
                             + tanhf(u) * sigf(ig);
                    float hh = sigf(o) * tanhf(c);
                    size_t po = ((size_t)slot * NB + b) * NHID + h;
                    pnh[po] = hh;
                    pnc[po] = c;
                    lpart = fmaf(hh, q[h], lpart);
                }
#pragma unroll
                for (int off = 32; off > 0; off >>= 1) lpart += __shfl_down(lpart, off);
                if ((tid & 63) == 0) lred[tid >> 6] = lpart;
                __syncthreads();
                if (tid == 0) plog_s[slot] = (lred[0] + lred[1]) + (lred[2] + lred[3]);
                __syncthreads();
            }

            // Phase B: argmax (first-index tie-break)
            const int actb = lenb - 1 - i;
            const int merge = actb >= 1;
            if (tid < 64) {
                float v = -1e30f;
                int idx = tid;
                if (tid < actb && tid < 31) v = plog_s[pidx_s[tid]];
#pragma unroll
                for (int off = 32; off > 0; off >>= 1) {
                    float ov = __shfl_down(v, off);
                    int   oi = __shfl_down(idx, off);
                    if (ov > v || (ov == v && oi < idx)) { v = ov; idx = oi; }
                }
                if (tid == 0) s_k = idx;
            }
            __syncthreads();
            const int k = s_k;
            const int last = (i == 30);

            // Phase C: node output + new state (or final hf/cf)
            float* noderow = out + 2 * BH + ((size_t)b * 63 + 32 + i) * NHID;
            if (merge) {
                const int kslot = pidx_s[k];
                const int ns = hidx_s[k];
                for (int h = tid; h < NHID; h += 256) {
                    size_t po = ((size_t)kslot * NB + b) * NHID + h;
                    float x = pnh[po], cc = pnc[po];
                    _Float16 hh = (_Float16)x;
                    size_t so = ((size_t)ns * NB + b) * NHID + h;
                    hHi[so] = hh;
                    hLo[so] = (_Float16)((x - (float)hh) * 2048.f);
                    cSt[so] = cc;
                    noderow[h] = x;
                    if (last) { out[b * NHID + h] = x; out[BH + b * NHID + h] = cc; }
                }
            } else {
                const int s0p = pidx_s[0], s0h = hidx_s[0];
                for (int h = tid; h < NHID; h += 256) {
                    if (!last) {
                        noderow[h] = pnh[((size_t)s0p * NB + b) * NHID + h];
                    } else {
                        size_t so = ((size_t)s0h * NB + b) * NHID + h;
                        float x = (float)hHi[so] + (float)hLo[so] * INV2048;
                        noderow[h] = x;
                        out[b * NHID + h] = x;
                        out[BH + b * NHID + h] = cSt[so];
                    }
                }
            }
            __syncthreads();   // drain state stores before publish

            // Phase D: bookkeeping + publish next step
            if (i < 30) {
                if (tid == 0) {
                    const int np = (i + 1) & 1;
                    if (merge) {
                        const int sp_k = pidx_s[k], sh_k = hidx_s[k];
                        const int sh_k2 = (k + 2 <= 31) ? hidx_s[k + 2] : HSLOT_Z;
                        const int nd = (k >= 1) ? 2 : 1;
                        int sp_km1 = 0, sh_km1 = 0;
                        if (k >= 1) { sp_km1 = pidx_s[k - 1]; sh_km1 = hidx_s[k - 1]; }
                        const int sp_k1 = pidx_s[k + 1];   // k<=30 -> in-bounds
                        for (int j2 = k + 1; j2 <= 29; ++j2) pidx_s[j2] = pidx_s[j2 + 1];
                        if (k < 30) pidx_s[30] = sp_k1;
                        for (int pp = k + 1; pp <= 30; ++pp) hidx_s[pp] = hidx_s[pp + 1];
                        hidx_s[31] = HSLOT_Z;
                        if (nd == 2) {
                            dsc[np * 64 + 2 * b]     = make_int4(sp_km1, sh_km1, sh_k, 1);
                            dsc[np * 64 + 2 * b + 1] = make_int4(sp_k, sh_k, sh_k2, 1);
                            s_fslot[0] = sp_km1; s_fls[0] = sh_km1; s_frs[0] = sh_k;
                            s_fslot[1] = sp_k;   s_fls[1] = sh_k;   s_frs[1] = sh_k2;
                        } else {
                            dsc[np * 64 + 2 * b]     = make_int4(sp_k, sh_k, sh_k2, 1);
                            dsc[np * 64 + 2 * b + 1] = make_int4(0, HSLOT_Z, HSLOT_Z, 0);
                            s_fslot[0] = sp_k; s_fls[0] = sh_k; s_frs[0] = sh_k2;
                        }
                        s_nf = nd;
                    } else {
                        dsc[np * 64 + 2 * b]     = make_int4(0, HSLOT_Z, HSLOT_Z, 0);
                        dsc[np * 64 + 2 * b + 1] = make_int4(0, HSLOT_Z, HSLOT_Z, 0);
                        s_nf = 0;
                    }
                    __builtin_amdgcn_fence(__ATOMIC_RELEASE, "agent");  // flush state+dsc
                    ainc_relaxed(&pubCnt[i + 1]);
                }
                __syncthreads();
            }
        }
    }
}

extern "C" void kernel_launch(void* const* d_in, const int* in_sizes, int n_in,
                              void* d_out, int out_size, void* d_ws, size_t ws_size,
                              hipStream_t stream) {
    const float* inp    = (const float*)d_in[0];
    const int*   length = (const int*)d_in[1];
    const float* W_word = (const float*)d_in[2];
    const float* b_word = (const float*)d_in[3];
    const float* W_comp = (const float*)d_in[4];
    const float* b_comp = (const float*)d_in[5];
    const float* q      = (const float*)d_in[6];
    float* out = (float*)d_out;
    float* ws  = (float*)d_ws;

    float*     gb0  = ws + OFF_GB0;
    float*     gbS  = ws + OFF_GBS;
    float*     pnh  = ws + OFF_PNH;
    float*     pnc  = ws + OFF_PNC;
    float*     cSt  = ws + OFF_CST;
    _Float16*  hHi  = (_Float16*)(ws + OFF_HHI);
    _Float16*  hLo  = (_Float16*)(ws + OFF_HLO);
    _Float16*  Wth  = (_Float16*)(ws + OFF_WTH);
    _Float16*  Wtl  = (_Float16*)(ws + OFF_WTL);
    int*       sy   = (int*)(ws + OFF_SYNC);
    int4*      dsc  = (int4*)(ws + OFF_DESC);

    init_kernel<<<2, 256, 0, stream>>>(hHi, hLo, cSt, sy);
    wsplit_kernel<<<dim3(NC5 / 32, 1024 / 32), 256, 0, stream>>>(W_comp, Wth, Wtl);
    word_gemm64<<<dim3(16, 16), 256, 0, stream>>>(inp, W_word, b_word,
                                                  hHi, hLo, cSt, out);
    tree_persist<<<NGB + NMB, 256, 0, stream>>>(hHi, hLo, cSt, Wth, Wtl,
                                                b_comp, q, length,
                                                gb0, gbS, pnh, pnc,
                                                dsc, sy, out);
}

// Round 9
// 1087.761 us; speedup vs baseline: 1.2560x; 1.0525x over previous
//
#include <hip/hip_runtime.h>
#include <math.h>

// Problem constants
constexpr int NB = 32, NL = 32, ND = 512, NHID = 512, NSTEPS = 31;
constexpr int NC5 = 2560;          // 5H
constexpr int BH = NB * NHID;      // 16384
constexpr int HSLOT_Z = 32;        // zero h slot
constexpr int HSLOT_N0 = 33;       // node created at step i -> h slot 33+i (write-once)
constexpr int NHS = 63;            // h slots 0..62 (33+29 max; last step writes none)
constexpr int CROW_Z = 32;         // zero c row (33 physical c rows, reused)
constexpr int NGB = 80;            // GEMM worker blocks (1 per n-tile)
constexpr int NMB = 32;            // merge worker blocks (1/batch)

constexpr float INV2048 = 1.f / 2048.f;

typedef _Float16 half8 __attribute__((ext_vector_type(8)));
typedef _Float16 half4 __attribute__((ext_vector_type(4)));
typedef float    f32x16 __attribute__((ext_vector_type(16)));

// ---------------- workspace layout (float offsets), 31.7 MB total ----------------
constexpr size_t OFF_GB0  = 0;                                   // [31][32][2560]
constexpr size_t OFF_GBS  = OFF_GB0 + (size_t)31 * NB * NC5;     // [64][2560] single buf
constexpr size_t OFF_PNH  = OFF_GBS + (size_t)64 * NC5;          // [31][32][512]
constexpr size_t OFF_PNC  = OFF_PNH + (size_t)31 * NB * NHID;
constexpr size_t OFF_CST  = OFF_PNC + (size_t)31 * NB * NHID;    // [33][32][512]
constexpr size_t OFF_HHI  = OFF_CST + (size_t)33 * NB * NHID;    // halves [63][32][512]
constexpr size_t OFF_HLO  = OFF_HHI + (size_t)NHS * NB * NHID / 2;
constexpr size_t OFF_WTH  = OFF_HLO + (size_t)NHS * NB * NHID / 2;
constexpr size_t OFF_WTL  = OFF_WTH + (size_t)NC5 * 1024 / 2;
constexpr size_t OFF_SYNC = OFF_WTL + (size_t)NC5 * 1024 / 2;    // 4096 ints reserved
constexpr size_t OFF_DESC = OFF_SYNC + 4096;                     // int4[31][64] (no overlap!)
// sync region: gflag[31][80] at +0 (2480), mflag[31][32] at +2480 (992) -> 3472 <= 4096

__device__ __forceinline__ float sigf(float x) { return 1.f / (1.f + expf(-x)); }

__device__ __forceinline__ int aload(int* p) {
    return __hip_atomic_load(p, __ATOMIC_RELAXED, __HIP_MEMORY_SCOPE_AGENT);
}
__device__ __forceinline__ void spin_flag(int* p) {
    int guard = 0;
    while (aload(p) == 0) {
        __builtin_amdgcn_s_sleep(2);
        if (++guard > 4000000) break;    // degrade to wrong-answer, not hang
    }
}
__device__ __forceinline__ void set_flag(int* p) {
    __hip_atomic_store(p, 1, __ATOMIC_RELAXED, __HIP_MEMORY_SCOPE_AGENT);
}
__device__ __forceinline__ float cload(const float* p) {   // coherence-point load
    return __hip_atomic_load((float*)p, __ATOMIC_RELAXED, __HIP_MEMORY_SCOPE_AGENT);
}
__device__ __forceinline__ void cstore(float* p, float v) { // coherence-point store
    __hip_atomic_store(p, v, __ATOMIC_RELAXED, __HIP_MEMORY_SCOPE_AGENT);
}

// ---------------- init: zero slot/row + sync flags ----------------
__global__ __launch_bounds__(256) void init_kernel(
    _Float16* __restrict__ hHi, _Float16* __restrict__ hLo,
    float* __restrict__ cSt, int* __restrict__ sync_)
{
    const int tid = threadIdx.x;
    if (blockIdx.x == 0) {
        const size_t zb = (size_t)HSLOT_Z * NB * NHID;
        const size_t zc = (size_t)CROW_Z * NB * NHID;
        for (int i = tid; i < NB * NHID; i += 256) {
            hHi[zb + i] = (_Float16)0.f;
            hLo[zb + i] = (_Float16)0.f;
            cSt[zc + i] = 0.f;
        }
    } else {
        for (int i = tid; i < 4096; i += 256) sync_[i] = 0;
    }
}

// ---------------- W_comp -> transposed split fp16 planes ----------------
__global__ __launch_bounds__(256) void wsplit_kernel(
    const float* __restrict__ W, _Float16* __restrict__ Wth, _Float16* __restrict__ Wtl)
{
    __shared__ float t[32][33];
    const int n0 = blockIdx.x * 32, k0 = blockIdx.y * 32;
    const int tid = threadIdx.x;
    const int c = tid & 31, r8 = tid >> 5;
#pragma unroll
    for (int p = 0; p < 4; ++p) {
        int r = p * 8 + r8;
        t[r][c] = W[(size_t)(k0 + r) * NC5 + n0 + c];
    }
    __syncthreads();
    const int nl = tid >> 3, k4 = (tid & 7) * 4;
    half4 vh, vl;
#pragma unroll
    for (int i = 0; i < 4; ++i) {
        float v = t[k4 + i][nl];
        _Float16 hh = (_Float16)v;
        vh[i] = hh;
        vl[i] = (_Float16)((v - (float)hh) * 2048.f);
    }
    size_t o = (size_t)(n0 + nl) * 1024 + k0 + k4;
    *(half4*)&Wth[o] = vh;
    *(half4*)&Wtl[o] = vl;
}

// ---------------- word GEMM: leaves -> h slots 0..31, c rows 0..31 ----------------
__global__ __launch_bounds__(256) void word_gemm64(
    const float* __restrict__ A, const float* __restrict__ W,
    const float* __restrict__ bias,
    _Float16* __restrict__ hi0, _Float16* __restrict__ lo0,
    float* __restrict__ cst, float* __restrict__ out)
{
    const int m0 = blockIdx.x * 64;
    const int n0 = blockIdx.y * 64;
    const int tid = threadIdx.x;
    const int tx = tid & 15, ty = tid >> 4;
    __shared__ float As[16][64];
    __shared__ float Bs[16][64];
    float acc[4][4];
#pragma unroll
    for (int i = 0; i < 4; ++i)
#pragma unroll
        for (int j = 0; j < 4; ++j) acc[i][j] = 0.f;

    for (int kt = 0; kt < ND; kt += 16) {
        {
            int row = tid >> 2, kq = tid & 3;
            float4 v = *(const float4*)(A + (size_t)(m0 + row) * ND + kt + kq * 4);
            As[kq * 4 + 0][row] = v.x;
            As[kq * 4 + 1][row] = v.y;
            As[kq * 4 + 2][row] = v.z;
            As[kq * 4 + 3][row] = v.w;
            int kr = tid >> 4, nq = tid & 15;
            float4 vb = *(const float4*)(W + (size_t)(kt + kr) * 1024 + n0 + nq * 4);
            *(float4*)&Bs[kr][nq * 4] = vb;
        }
        __syncthreads();
#pragma unroll
        for (int kk = 0; kk < 16; ++kk) {
            float a0 = As[kk][ty * 4 + 0], a1 = As[kk][ty * 4 + 1];
            float a2 = As[kk][ty * 4 + 2], a3 = As[kk][ty * 4 + 3];
            float4 bv = *(float4*)&Bs[kk][tx * 4];
            acc[0][0] = fmaf(a0, bv.x, acc[0][0]); acc[0][1] = fmaf(a0, bv.y, acc[0][1]);
            acc[0][2] = fmaf(a0, bv.z, acc[0][2]); acc[0][3] = fmaf(a0, bv.w, acc[0][3]);
            acc[1][0] = fmaf(a1, bv.x, acc[1][0]); acc[1][1] = fmaf(a1, bv.y, acc[1][1]);
            acc[1][2] = fmaf(a1, bv.z, acc[1][2]); acc[1][3] = fmaf(a1, bv.w, acc[1][3]);
            acc[2][0] = fmaf(a2, bv.x, acc[2][0]); acc[2][1] = fmaf(a2, bv.y, acc[2][1]);
            acc[2][2] = fmaf(a2, bv.z, acc[2][2]); acc[2][3] = fmaf(a2, bv.w, acc[2][3]);
            acc[3][0] = fmaf(a3, bv.x, acc[3][0]); acc[3][1] = fmaf(a3, bv.y, acc[3][1]);
            acc[3][2] = fmaf(a3, bv.z, acc[3][2]); acc[3][3] = fmaf(a3, bv.w, acc[3][3]);
        }
        __syncthreads();
    }
    float* nodes = out + 2 * BH;
#pragma unroll
    for (int i = 0; i < 4; ++i) {
        int r = m0 + ty * 4 + i;
        int b = r >> 5, l = r & 31;
#pragma unroll
        for (int jn = 0; jn < 4; ++jn) {
            int n = n0 + tx * 4 + jn;
            float v = acc[i][jn] + bias[n];
            if (n < NHID) {
                size_t si = ((size_t)l * NB + b) * NHID + n;
                _Float16 hh = (_Float16)v;
                hi0[si] = hh;
                lo0[si] = (_Float16)((v - (float)hh) * 2048.f);
                nodes[((size_t)b * 63 + l) * NHID + n] = v;
            } else {
                cst[((size_t)l * NB + b) * NHID + (n - NHID)] = v;
            }
        }
    }
}

// 32x32 split-fp16 3-product MFMA tile; K split over 4 waves; cross-wave
// reduce through LDS; raw gates (no bias) via coherent stores to dstRow0.
__device__ __forceinline__ void gemm_tile32(
    const _Float16* __restrict__ aHiP, const _Float16* __restrict__ aLoP,
    const _Float16* __restrict__ bHiP, const _Float16* __restrict__ bLoP,
    float* __restrict__ red, float* __restrict__ dstRow0, int ntOff,
    int kw, int l5, int ln, int tid)
{
    f32x16 acc1 = (f32x16)0.f, acc2 = (f32x16)0.f;
#pragma unroll
    for (int ks = 0; ks < 16; ++ks) {
        const int ko = ks * 16;
        half8 Ah = *(const half8*)(aHiP + ko);
        half8 Al = *(const half8*)(aLoP + ko);
        half8 Bh = *(const half8*)(bHiP + ko);
        half8 Bl = *(const half8*)(bLoP + ko);
        acc1 = __builtin_amdgcn_mfma_f32_32x32x16_f16(Ah, Bh, acc1, 0, 0, 0);
        acc2 = __builtin_amdgcn_mfma_f32_32x32x16_f16(Ah, Bl, acc2, 0, 0, 0);
        acc2 = __builtin_amdgcn_mfma_f32_32x32x16_f16(Al, Bh, acc2, 0, 0, 0);
    }
    __syncthreads();                      // red free from previous use
#pragma unroll
    for (int a = 0; a < 16; ++a) {
        int row = (a & 3) + 8 * (a >> 2) + 4 * l5;
        red[(kw * 32 + row) * 32 + ln] = acc1[a] + acc2[a] * INV2048;
    }
    __syncthreads();
    {
        const int row = tid >> 3, c0 = (tid & 7) * 4;
        float* dp = dstRow0 + (size_t)row * NC5 + ntOff + c0;
#pragma unroll
        for (int jj = 0; jj < 4; ++jj) {
            float s = (red[(0 * 32 + row) * 32 + c0 + jj] + red[(1 * 32 + row) * 32 + c0 + jj])
                    + (red[(2 * 32 + row) * 32 + c0 + jj] + red[(3 * 32 + row) * 32 + c0 + jj]);
            cstore(dp + jj, s);           // write-through to coherence point
        }
    }
}

// ---------------- the persistent tree kernel (fence-free) ----------------
// Blocks 0..79: GEMM workers (nt = blk fixed -> W slice stays L2-hot).
// Blocks 80..111: merge workers (1/batch).
// Cross-block mutable data: sc1 coherent accesses (gates, fresh h, dsc-write).
// h-slots and dsc are versioned (write-once) -> consumer plain loads are safe
// (dispatch-start cache invalidate clears harness poison lines).
// c rows are PRIVATE to their merge worker -> plain access + in-place reuse.
__global__ __launch_bounds__(256) void tree_persist(
    _Float16* __restrict__ hHi, _Float16* __restrict__ hLo, float* __restrict__ cSt,
    const _Float16* __restrict__ Wth, const _Float16* __restrict__ Wtl,
    const float* __restrict__ bias, const float* __restrict__ q,
    const int* __restrict__ len,
    float* __restrict__ gb0, float* __restrict__ gbS,
    float* __restrict__ pnh, float* __restrict__ pnc,
    int4* __restrict__ dsc, int* __restrict__ sync_, float* __restrict__ out)
{
    int* gflag = sync_;          // [31][80]: GEMM blk done with step i
    int* mflag = sync_ + 2480;   // [31][32]: batch b's step-i descriptors ready
    const int blk = blockIdx.x, tid = threadIdx.x;

    if (blk < NGB) {
        // ================= GEMM worker =================
        __shared__ float red[4 * 32 * 32];
        const int kw = tid >> 6, lane = tid & 63;
        const int l5 = lane >> 5, ln = lane & 31;
        const int koff = (kw & 1) * 256 + l5 * 8;   // k offset inside one 512 half
        const int nt = blk;
        const _Float16* bH = Wth + ((size_t)(nt * 32 + ln)) * 1024 + (kw >> 1) * 512 + koff;
        const _Float16* bL = Wtl + ((size_t)(nt * 32 + ln)) * 1024 + (kw >> 1) * 512 + koff;

        // ---- step 0: all 992 pairs (j = mt, b = ln, left = mt, right = mt+1)
        for (int mt = 0; mt < 31; ++mt) {
            const int hs = (kw < 2) ? mt : mt + 1;
            const _Float16* aH = hHi + ((size_t)hs * NB + ln) * NHID + koff;
            const _Float16* aL = hLo + ((size_t)hs * NB + ln) * NHID + koff;
            gemm_tile32(aH, aL, bH, bL, red, gb0 + (size_t)(mt * 32) * NC5,
                        nt * 32, kw, l5, ln, tid);
        }
        __syncthreads();                            // drains all waves' vmcnt
        if (tid == 0) set_flag(&gflag[0 * 80 + blk]);

        // ---- steps 1..30: 64 fresh rows (2/batch), desc-driven, both m-tiles
        for (int i = 1; i <= 30; ++i) {
            if (tid < 32) spin_flag(&mflag[i * 32 + tid]);
            __syncthreads();
            asm volatile("" ::: "memory");
#pragma unroll
            for (int mt = 0; mt < 2; ++mt) {
                const int r = mt * 32 + ln;
                const int bb = r >> 1;
                const int4 d = dsc[i * 64 + r];     // {slot, left, right, active}
                const int hs = (kw < 2) ? d.y : d.z;
                const _Float16* aH = hHi + ((size_t)hs * NB + bb) * NHID + koff;
                const _Float16* aL = hLo + ((size_t)hs * NB + bb) * NHID + koff;
                gemm_tile32(aH, aL, bH, bL, red, gbS + (size_t)(mt * 32) * NC5,
                            nt * 32, kw, l5, ln, tid);
            }
            __syncthreads();
            if (tid == 0) set_flag(&gflag[i * 80 + blk]);
        }
    } else if (blk < NGB + NMB) {
        // ================= merge worker (batch b) =================
        const int b = blk - NGB;
        __shared__ int pidx_s[32], hidx_s[32], chidx_s[32];
        __shared__ float plog_s[31];
        __shared__ float lred[4];
        __shared__ int s_k, s_nf, s_fslot[2], s_fcl[2], s_fcr[2];
        if (tid < 32) { pidx_s[tid] = min(tid, 30); hidx_s[tid] = tid; chidx_s[tid] = tid; }
        __syncthreads();
        const int lenb = len[b];

        for (int i = 0; i <= 30; ++i) {
            if (tid < 80) spin_flag(&gflag[i * 80 + tid]);
            __syncthreads();
            asm volatile("" ::: "memory");

            // Phase A: act + logit for fresh pairs (gates via coherent loads)
            const int nf = (i == 0) ? 31 : s_nf;
            for (int f = 0; f < nf; ++f) {
                int slot, cls, crs; const float* gr;
                if (i == 0) { slot = f; cls = f; crs = f + 1;
                              gr = gb0 + ((size_t)(f * 32 + b)) * NC5; }
                else        { slot = s_fslot[f]; cls = s_fcl[f]; crs = s_fcr[f];
                              gr = gbS + ((size_t)(2 * b + f)) * NC5; }
                const float* clp = cSt + ((size_t)cls * NB + b) * NHID;
                const float* crp = cSt + ((size_t)crs * NB + b) * NHID;
                float lpart = 0.f;
                for (int h = tid; h < NHID; h += 256) {
                    float ig = cload(gr + h)        + bias[h];
                    float fl = cload(gr + 512 + h)  + bias[512 + h];
                    float fr = cload(gr + 1024 + h) + bias[1024 + h];
                    float u  = cload(gr + 1536 + h) + bias[1536 + h];
                    float o  = cload(gr + 2048 + h) + bias[2048 + h];
                    float cl = clp[h], cr = crp[h];
                    float c  = cl * sigf(fl + 1.f) + cr * sigf(fr + 1.f)
                             + tanhf(u) * sigf(ig);
                    float hh = sigf(o) * tanhf(c);
                    size_t po = ((size_t)slot * NB + b) * NHID + h;
                    pnh[po] = hh;                   // private to this block
                    pnc[po] = c;
                    lpart = fmaf(hh, q[h], lpart);
                }
#pragma unroll
                for (int off = 32; off > 0; off >>= 1) lpart += __shfl_down(lpart, off);
                if ((tid & 63) == 0) lred[tid >> 6] = lpart;
                __syncthreads();
                if (tid == 0) plog_s[slot] = (lred[0] + lred[1]) + (lred[2] + lred[3]);
                __syncthreads();
            }

            // Phase B: argmax (first-index tie-break)
            const int actb = lenb - 1 - i;
            const int merge = actb >= 1;
            if (tid < 64) {
                float v = -1e30f;
                int idx = tid;
                if (tid < actb && tid < 31) v = plog_s[pidx_s[tid]];
#pragma unroll
                for (int off = 32; off > 0; off >>= 1) {
                    float ov = __shfl_down(v, off);
                    int   oi = __shfl_down(idx, off);
                    if (ov > v || (ov == v && oi < idx)) { v = ov; idx = oi; }
                }
                if (tid == 0) s_k = idx;
            }
            __syncthreads();
            const int k = s_k;
            const int last = (i == 30);

            // Phase C: node output + (if not last) new write-once h slot 33+i
            // and c reuse into the left child's physical row chidx_s[k].
            float* noderow = out + 2 * BH + ((size_t)b * 63 + 32 + i) * NHID;
            const int h0 = tid * 2;                 // 256 threads x 2 = 512
            if (merge) {
                const int kslot = pidx_s[k];
                size_t po = ((size_t)kslot * NB + b) * NHID + h0;
                float x0 = pnh[po], x1 = pnh[po + 1];
                float c0 = pnc[po], c1 = pnc[po + 1];
                noderow[h0] = x0; noderow[h0 + 1] = x1;
                if (!last) {
                    const int ns = HSLOT_N0 + i;    // fresh h slot, never reused
                    const int ncr = chidx_s[k];     // left child's c row, reused
                    _Float16 hh0 = (_Float16)x0, hh1 = (_Float16)x1;
                    _Float16 hl0 = (_Float16)((x0 - (float)hh0) * 2048.f);
                    _Float16 hl1 = (_Float16)((x1 - (float)hh1) * 2048.f);
                    size_t so = ((size_t)ns * NB + b) * NHID + h0;
                    union { _Float16 h[2]; unsigned int u; } phi, plo;
                    phi.h[0] = hh0; phi.h[1] = hh1;
                    plo.h[0] = hl0; plo.h[1] = hl1;
                    // write-through so GEMM workers' first-touch miss sees it
                    __hip_atomic_store((unsigned int*)(hHi + so), phi.u,
                                       __ATOMIC_RELAXED, __HIP_MEMORY_SCOPE_AGENT);
                    __hip_atomic_store((unsigned int*)(hLo + so), plo.u,
                                       __ATOMIC_RELAXED, __HIP_MEMORY_SCOPE_AGENT);
                    size_t co = ((size_t)ncr * NB + b) * NHID + h0;
                    cSt[co] = c0; cSt[co + 1] = c1; // private (this batch only)
                } else {
                    out[b * NHID + h0] = x0;      out[b * NHID + h0 + 1] = x1;
                    out[BH + b * NHID + h0] = c0; out[BH + b * NHID + h0 + 1] = c1;
                }
            } else {
                const int s0p = pidx_s[0];
                if (!last) {
                    size_t po = ((size_t)s0p * NB + b) * NHID + h0;
                    noderow[h0] = pnh[po]; noderow[h0 + 1] = pnh[po + 1];
                } else {
                    const int s0h = hidx_s[0], s0c = chidx_s[0];
                    size_t so = ((size_t)s0h * NB + b) * NHID + h0;
                    size_t co = ((size_t)s0c * NB + b) * NHID + h0;
                    float x0 = (float)hHi[so] + (float)hLo[so] * INV2048;
                    float x1 = (float)hHi[so + 1] + (float)hLo[so + 1] * INV2048;
                    noderow[h0] = x0; noderow[h0 + 1] = x1;
                    out[b * NHID + h0] = x0;      out[b * NHID + h0 + 1] = x1;
                    out[BH + b * NHID + h0] = cSt[co]; out[BH + b * NHID + h0 + 1] = cSt[co + 1];
                }
            }
            __syncthreads();   // drains all waves' stores (incl. sc1 state writes)

            // Phase D: bookkeeping + publish next step (descs via write-through)
            if (i < 30) {
                if (tid == 0) {
                    unsigned long long d0a, d0b, d1a, d1b;
                    if (merge) {
                        const int N = HSLOT_N0 + i;
                        const int ncr = chidx_s[k];
                        const int sp_k = pidx_s[k];
                        const int sh_D = (k + 2 <= 31) ? hidx_s[k + 2] : HSLOT_Z;
                        const int sc_D = (k + 2 <= 31) ? chidx_s[k + 2] : CROW_Z;
                        const int nd = (k >= 1) ? 2 : 1;
                        int sp_km1 = 0, sh_A = 0, sc_A = 0;
                        if (k >= 1) { sp_km1 = pidx_s[k - 1]; sh_A = hidx_s[k - 1];
                                      sc_A = chidx_s[k - 1]; }
                        const int sp_k1 = pidx_s[k + 1];
                        for (int j2 = k + 1; j2 <= 29; ++j2) pidx_s[j2] = pidx_s[j2 + 1];
                        if (k < 30) pidx_s[30] = sp_k1;
                        hidx_s[k] = N;              // chidx_s[k] already = ncr (reuse)
                        for (int pp = k + 1; pp <= 30; ++pp) {
                            hidx_s[pp] = hidx_s[pp + 1];
                            chidx_s[pp] = chidx_s[pp + 1];
                        }
                        hidx_s[31] = HSLOT_Z;
                        chidx_s[31] = CROW_Z;
                        if (nd == 2) {
                            d0a = (unsigned long long)(unsigned)sp_km1
                                | ((unsigned long long)(unsigned)sh_A << 32);
                            d0b = (unsigned long long)(unsigned)N | (1ull << 32);
                            d1a = (unsigned long long)(unsigned)sp_k
                                | ((unsigned long long)(unsigned)N << 32);
                            d1b = (unsigned long long)(unsigned)sh_D | (1ull << 32);
                            s_fslot[0] = sp_km1; s_fcl[0] = sc_A; s_fcr[0] = ncr;
                            s_fslot[1] = sp_k;   s_fcl[1] = ncr;  s_fcr[1] = sc_D;
                        } else {
                            d0a = (unsigned long long)(unsigned)sp_k
                                | ((unsigned long long)(unsigned)N << 32);
                            d0b = (unsigned long long)(unsigned)sh_D | (1ull << 32);
                            d1a = 0ull | ((unsigned long long)(unsigned)HSLOT_Z << 32);
                            d1b = (unsigned long long)(unsigned)HSLOT_Z;
                            s_fslot[0] = sp_k; s_fcl[0] = ncr; s_fcr[0] = sc_D;
                        }
                        s_nf = nd;
                    } else {
                        d0a = 0ull | ((unsigned long long)(unsigned)HSLOT_Z << 32);
                        d0b = (unsigned long long)(unsigned)HSLOT_Z;
                        d1a = d0a; d1b = d0b;
                        s_nf = 0;
                    }
                    unsigned long long* dp =
                        (unsigned long long*)&dsc[(i + 1) * 64 + 2 * b];
                    __hip_atomic_store(dp + 0, d0a, __ATOMIC_RELAXED, __HIP_MEMORY_SCOPE_AGENT);
                    __hip_atomic_store(dp + 1, d0b, __ATOMIC_RELAXED, __HIP_MEMORY_SCOPE_AGENT);
                    __hip_atomic_store(dp + 2, d1a, __ATOMIC_RELAXED, __HIP_MEMORY_SCOPE_AGENT);
                    __hip_atomic_store(dp + 3, d1b, __ATOMIC_RELAXED, __HIP_MEMORY_SCOPE_AGENT);
                    __builtin_amdgcn_s_waitcnt(0);  // dsc stores at coherence point
                    set_flag(&mflag[(i + 1) * 32 + b]);
                }
                __syncthreads();
            }
        }
    }
}

extern "C" void kernel_launch(void* const* d_in, const int* in_sizes, int n_in,
                              void* d_out, int out_size, void* d_ws, size_t ws_size,
                              hipStream_t stream) {
    const float* inp    = (const float*)d_in[0];
    const int*   length = (const int*)d_in[1];
    const float* W_word = (const float*)d_in[2];
    const float* b_word = (const float*)d_in[3];
    const float* W_comp = (const float*)d_in[4];
    const float* b_comp = (const float*)d_in[5];
    const float* q      = (const float*)d_in[6];
    float* out = (float*)d_out;
    float* ws  = (float*)d_ws;

    float*     gb0  = ws + OFF_GB0;
    float*     gbS  = ws + OFF_GBS;
    float*     pnh  = ws + OFF_PNH;
    float*     pnc  = ws + OFF_PNC;
    float*     cSt  = ws + OFF_CST;
    _Float16*  hHi  = (_Float16*)(ws + OFF_HHI);
    _Float16*  hLo  = (_Float16*)(ws + OFF_HLO);
    _Float16*  Wth  = (_Float16*)(ws + OFF_WTH);
    _Float16*  Wtl  = (_Float16*)(ws + OFF_WTL);
    int*       sy   = (int*)(ws + OFF_SYNC);
    int4*      dsc  = (int4*)(ws + OFF_DESC);

    init_kernel<<<2, 256, 0, stream>>>(hHi, hLo, cSt, sy);
    wsplit_kernel<<<dim3(NC5 / 32, 1024 / 32), 256, 0, stream>>>(W_comp, Wth, Wtl);
    word_gemm64<<<dim3(16, 16), 256, 0, stream>>>(inp, W_word, b_word,
                                                  hHi, hLo, cSt, out);
    tree_persist<<<NGB + NMB, 256, 0, stream>>>(hHi, hLo, cSt, Wth, Wtl,
                                                b_comp, q, length,
                                                gb0, gbS, pnh, pnc,
                                                dsc, sy, out);
}